// Round 7
// baseline (321.318 us; speedup 1.0000x reference)
//
#include <hip/hip_runtime.h>
#include <hip/hip_bf16.h>

typedef unsigned short u16;
using f32x4  = __attribute__((ext_vector_type(4))) float;
using bf16x8 = __attribute__((ext_vector_type(8))) short;

#define N_B 4
#define N_S 4096
#define N_C 1280
#define N_DC 2048
#define N_H 20
#define N_D 64

__device__ __forceinline__ u16 f2b(float f) {
  union { float f; unsigned u; } x; x.f = f;
  return (u16)((x.u + 0x7fffu + ((x.u >> 16) & 1u)) >> 16);
}

__device__ __forceinline__ void gld16(const u16* g, u16* l) {
  __builtin_amdgcn_global_load_lds(
      (const __attribute__((address_space(1))) unsigned int*)(g),
      (__attribute__((address_space(3))) unsigned int*)(l), 16, 0, 0);
}

// ---------- hs f32 -> bf16
__global__ void k_cvt(const float* __restrict__ src, u16* __restrict__ dst, int n8) {
  for (int i = blockIdx.x * 256 + threadIdx.x; i < n8; i += gridDim.x * 256) {
    const float4 v0 = *(const float4*)(src + (size_t)i * 8);
    const float4 v1 = *(const float4*)(src + (size_t)i * 8 + 4);
    alignas(16) u16 t[8];
    t[0] = f2b(v0.x); t[1] = f2b(v0.y); t[2] = f2b(v0.z); t[3] = f2b(v0.w);
    t[4] = f2b(v1.x); t[5] = f2b(v1.y); t[6] = f2b(v1.z); t[7] = f2b(v1.w);
    *(uint4*)(dst + (size_t)i * 8) = *(uint4*)t;
  }
}

// ---------- batched weight transpose + bf16
struct TPargs { const float* s[8]; u16* d[8]; int K[8]; };

__global__ void k_transpose8(TPargs a) {
  int z = blockIdx.z;
  const float* __restrict__ src = a.s[z];
  u16* __restrict__ dst = a.d[z];
  int K = a.K[z];
  int k0 = blockIdx.y * 32;
  if (k0 >= K) return;
  __shared__ float tl[32][33];
  int n0 = blockIdx.x * 32;
  int tx = threadIdx.x, ty = threadIdx.y;
#pragma unroll
  for (int j = 0; j < 32; j += 8)
    tl[ty + j][tx] = src[(size_t)(k0 + ty + j) * N_C + (n0 + tx)];
  __syncthreads();
#pragma unroll
  for (int j = 0; j < 32; j += 8)
    dst[(size_t)(n0 + ty + j) * K + (k0 + tx)] = f2b(tl[tx][ty + j]);
}

// ---------- pack encoder rows
__global__ void k_encpack(const float* __restrict__ enc, u16* __restrict__ txt,
                          u16* __restrict__ img, u16* __restrict__ lbl) {
  int row = blockIdx.x;
  int b = row / 85, l = row % 85;
  const float* s = enc + (size_t)row * N_DC;
  u16* d;
  if (l < 77)      d = txt + (size_t)(b * 77 + l) * N_DC;
  else if (l < 81) d = img + (size_t)(b * 4 + (l - 77)) * N_DC;
  else             d = lbl + (size_t)(b * 4 + (l - 81)) * N_DC;
  for (int i = threadIdx.x; i < N_DC; i += 256) d[i] = f2b(s[i]);
}

// ================= 256x320 GEMM: A via LDS (dbuf), B global->reg ==========
// C[M x N] = A[M x K](bf16) * Bt[N x K]^T.  512 thr = 8 waves (2M x 4N),
// wave tile 128x80, BK=64.
// A: LDS double-buffer 2 x 32 KB (slot-XOR swizzle, global_load_lds).
// B: each wave loads its own 80-row fragment slice global->reg per K-tile
//    (L2-resident: B panel 0.8 MB re-read by 64 bm-blocks; no cross-wave
//    reuse to justify LDS). Removes 10/26 LDS reads + 40/72 KB staging
//    per tile -> LDS ~1800 cyc < MFMA ~3100 cyc per tile per CU.
// Compiler inserts counted vmcnt for B reg-loads; manual vmcnt(0) only
// drains the 4 A-prefetch gld at the tile boundary. 1 barrier per tile.
// Grid = (M/256)*(N/320) = 256 = one full round on 256 CUs.
// EPI: 1 = bf16 store * scale, 2 = f32 store + bias + resid

__device__ __forceinline__ void stage64(const u16* __restrict__ g, int ldK,
                                        int row0, int kk, u16* ldsb,
                                        int w, int lane) {
  int r = w * 8 + (lane >> 3);
  int gslot = ((lane & 7) ^ (lane >> 3)) << 3;
  gld16(g + (size_t)(row0 + r) * ldK + kk + gslot, ldsb + w * 512);
}
__device__ __forceinline__ void stageA4(const u16* Ag, int K, int kk, u16* ldsb,
                                        int w, int lane) {
#pragma unroll
  for (int j = 0; j < 4; j++)
    stage64(Ag, K, j * 64, kk, ldsb + j * 4096, w, lane);
}

#define RD_A2(aoff, mh)                                                      \
  _Pragma("unroll") for (int mi = 0; mi < 2; mi++) {                         \
    _Pragma("unroll") for (int ks = 0; ks < 2; ks++) {                       \
      int row = wr * 128 + ((mh) * 2 + mi) * 16 + lrow;                      \
      int slot = (ks * 4 + g) ^ (lane & 7);                                  \
      af[mi][ks] = *(const bf16x8*)&lds[(aoff) + row * 64 + slot * 8];       \
    }                                                                        \
  }

#define MFMA20(mh)                                                           \
  _Pragma("unroll") for (int mi = 0; mi < 2; mi++) {                         \
    _Pragma("unroll") for (int n = 0; n < 5; n++) {                          \
      _Pragma("unroll") for (int ks = 0; ks < 2; ks++)                       \
        acc[(mh) * 2 + mi][n] = __builtin_amdgcn_mfma_f32_16x16x32_bf16(     \
            af[mi][ks], bf[n][ks], acc[(mh) * 2 + mi][n], 0, 0, 0);          \
    }                                                                        \
  }

#define BARR()  __builtin_amdgcn_s_barrier()
#define VM0()   asm volatile("s_waitcnt vmcnt(0)" ::: "memory")
#define PRIO(x) __builtin_amdgcn_s_setprio(x)

template<int EPI>
__global__ __launch_bounds__(512, 1)
void gemm8p(const u16* __restrict__ A, const u16* __restrict__ Bt,
            void* __restrict__ Cv, int M, int N, int K, float scale,
            const float* __restrict__ bias, const float* __restrict__ resid) {
  __shared__ __align__(16) u16 lds[32768];   // A dbuf: [0,16384) / [16384,32768)
  const int t = threadIdx.x, lane = t & 63, w = t >> 6;
  const int wr = w >> 2, wc = w & 3;
  const int lrow = lane & 15, g = lane >> 4;

  int nt = N / 320;
  int nwg = gridDim.x, bid = blockIdx.x;
  int swz = ((nwg & 7) == 0) ? ((bid & 7) * (nwg >> 3) + (bid >> 3)) : bid;
  int bm = swz / nt, bn = swz % nt;

  const u16* Ag = A  + (size_t)bm * 256 * K;
  // per-lane B fragment base: row = bn*320 + wc*80 + lrow, k-offset g*8
  const u16* Bl = Bt + (size_t)(bn * 320 + wc * 80 + lrow) * K + g * 8;
  const int NT = K >> 6;

  f32x4 acc[8][5] = {};
  bf16x8 af[2][2], bf[5][2];

  // prologue: stage A tile0 -> buf0
  stageA4(Ag, K, 0, lds + 0, w, lane);
  VM0();
  BARR();

  for (int tt = 0; tt < NT; ++tt) {
    int c = tt & 1;
    int aof  = c * 16384;
    int aof1 = (c ^ 1) * 16384;
    // B fragments for this tile: plain global loads (compiler-counted vmcnt)
#pragma unroll
    for (int n = 0; n < 5; n++)
#pragma unroll
      for (int ks = 0; ks < 2; ks++)
        bf[n][ks] = *(const bf16x8*)(Bl + (size_t)n * 16 * K + tt * 64 + ks * 32);
    // prefetch A(t+1) into the other LDS buffer
    if (tt + 1 < NT) stageA4(Ag, K, (tt + 1) * 64, lds + aof1, w, lane);
    // straight-line compute on A buf c
    RD_A2(aof, 0);
    PRIO(1); MFMA20(0); PRIO(0);
    RD_A2(aof, 1);
    PRIO(1); MFMA20(1); PRIO(0);
    RD_A2(aof, 2);
    PRIO(1); MFMA20(2); PRIO(0);
    RD_A2(aof, 3);
    PRIO(1); MFMA20(3); PRIO(0);
    // tile boundary: A(t+1) staged, all reads of buf c consumed
    VM0();
    BARR();
  }

  // epilogue
#pragma unroll
  for (int m = 0; m < 8; m++) {
    int row = bm * 256 + wr * 128 + m * 16 + g * 4;
#pragma unroll
    for (int n = 0; n < 5; n++) {
      int col = bn * 320 + wc * 80 + n * 16 + lrow;
#pragma unroll
      for (int j = 0; j < 4; j++) {
        float v = acc[m][n][j];
        if constexpr (EPI == 1)
          ((u16*)Cv)[(size_t)(row + j) * N + col] = f2b(v * scale);
        else
          ((float*)Cv)[(size_t)(row + j) * N + col] =
              v + bias[col] + resid[(size_t)(row + j) * N + col];
      }
    }
  }
}

// ---------- all 6 KV projections in one launch, prefetched 2-phase
__global__ __launch_bounds__(256, 2)
void kv_gemm(const u16* __restrict__ etxt, const u16* __restrict__ eimg, const u16* __restrict__ elbl,
             const u16* __restrict__ wk,   const u16* __restrict__ wv,
             const u16* __restrict__ wkip, const u16* __restrict__ wvip,
             const u16* __restrict__ wklb, const u16* __restrict__ wvlb,
             u16* ktxt, u16* vtxt, u16* kimg, u16* vimg, u16* klbl, u16* vlbl) {
  __shared__ __align__(16) u16 lds[2][2][8192];   // [buf][A/B][128*64]
  int bn = blockIdx.x, my = blockIdx.y, kv = blockIdx.z;
  const u16 *A, *Bt; u16* C; int M, bm;
  if (my < 3)       { A = etxt; M = 308; bm = my; Bt = kv ? wv   : wk;   C = kv ? vtxt : ktxt; }
  else if (my == 3) { A = eimg; M = 16;  bm = 0;  Bt = kv ? wvip : wkip; C = kv ? vimg : kimg; }
  else              { A = elbl; M = 16;  bm = 0;  Bt = kv ? wvlb : wklb; C = kv ? vlbl : klbl; }
  const int K = 2048;
  int t = threadIdx.x, lane = t & 63, w = t >> 6;
  int wm = w >> 1, wn = w & 1;
  int c8 = lane & 7, rsub = lane >> 3;

  f32x4 acc[4][4] = {};

#define KVSTAGE(kt, buf)                                                      \
  {                                                                           \
    int k0 = (kt) * 64;                                                       \
    _Pragma("unroll") for (int i2 = 0; i2 < 4; i2++) {                        \
      int rloc = w * 32 + i2 * 8;                                             \
      int ra = bm * 128 + rloc + rsub; if (ra >= M) ra = M - 1;               \
      int rb = bn * 128 + rloc + rsub;                                        \
      gld16(A  + (size_t)ra * K + k0 + c8 * 8, &lds[buf][0][rloc * 64]);      \
      gld16(Bt + (size_t)rb * K + k0 + c8 * 8, &lds[buf][1][rloc * 64]);      \
    }                                                                         \
  }

  KVSTAGE(0, 0);
  asm volatile("s_waitcnt vmcnt(0)" ::: "memory");
  __syncthreads();
  int cur = 0;
  for (int kt = 0; kt < 32; kt++) {
    if (kt < 31) KVSTAGE(kt + 1, cur ^ 1);
#pragma unroll
    for (int ks = 0; ks < 2; ks++) {
      bf16x8 afr[4], bfr[4];
#pragma unroll
      for (int m = 0; m < 4; m++)
        afr[m] = *(bf16x8*)&lds[cur][0][(wm * 64 + m * 16 + (lane & 15)) * 64 + ks * 32 + (lane >> 4) * 8];
#pragma unroll
      for (int n = 0; n < 4; n++)
        bfr[n] = *(bf16x8*)&lds[cur][1][(wn * 64 + n * 16 + (lane & 15)) * 64 + ks * 32 + (lane >> 4) * 8];
#pragma unroll
      for (int m = 0; m < 4; m++)
#pragma unroll
        for (int n = 0; n < 4; n++)
          acc[m][n] = __builtin_amdgcn_mfma_f32_16x16x32_bf16(afr[m], bfr[n], acc[m][n], 0, 0, 0);
    }
    asm volatile("s_waitcnt vmcnt(0)" ::: "memory");
    __syncthreads();
    cur ^= 1;
  }
#undef KVSTAGE

#pragma unroll
  for (int m = 0; m < 4; m++) {
    int row = bm * 128 + wm * 64 + m * 16 + ((lane >> 4) << 2);
#pragma unroll
    for (int n = 0; n < 4; n++) {
      int col = bn * 128 + wn * 64 + n * 16 + (lane & 15);
#pragma unroll
      for (int j = 0; j < 4; j++) {
        int r = row + j;
        if (r >= M) continue;
        ((u16*)C)[(size_t)r * 1280 + col] = f2b(acc[m][n][j]);
      }
    }
  }
}

// ---------- fused attention (unchanged)
#define QSTR 72
#define PSTR 104

__global__ __launch_bounds__(256, 2)
void attn_kern(const u16* __restrict__ q,
               const u16* __restrict__ ktxt, const u16* __restrict__ vtxt,
               const u16* __restrict__ kimg, const u16* __restrict__ vimg,
               const u16* __restrict__ klbl, const u16* __restrict__ vlbl,
               u16* __restrict__ outa) {
  __shared__ __align__(16) char smem[45568];
  u16* Qs = (u16*)smem;
  u16* Ks = (u16*)(smem + 18432);
  u16* Ps = (u16*)smem;
  u16* Vt = (u16*)(smem + 32256);

  int st = blockIdx.x, h = blockIdx.y, b = blockIdx.z;
  int t = threadIdx.x, lane = t & 63, w = t >> 6;
  int s0 = st * 128;
  int c = lane & 15, g = lane >> 4;

  for (int i = t; i < 27136 / 16; i += 256)
    ((uint4*)(smem + 18432))[i] = make_uint4(0, 0, 0, 0);
#pragma unroll
  for (int i = 0; i < 4; i++) {
    int cid = t + i * 256; int r = cid >> 3, c8 = cid & 7;
    *(uint4*)&Qs[r * QSTR + c8 * 8] =
        *(const uint4*)(q + (size_t)(b * N_S + s0 + r) * N_C + h * N_D + c8 * 8);
  }
  __syncthreads();
  for (int cid = t; cid < 680; cid += 256) {
    int l = cid >> 3, c8 = cid & 7;
    const u16* p;
    if (l < 77)      p = ktxt + (size_t)(b * 77 + l) * N_C + h * N_D + c8 * 8;
    else if (l < 81) p = kimg + (size_t)(b * 4 + l - 77) * N_C + h * N_D + c8 * 8;
    else             p = klbl + (size_t)(b * 4 + l - 81) * N_C + h * N_D + c8 * 8;
    int row = (l < 77) ? l : l + 3;
    *(uint4*)&Ks[row * QSTR + c8 * 8] = *(const uint4*)p;
  }
  for (int e = t; e < 85 * 64; e += 256) {
    int l = e >> 6, d = e & 63;
    const u16* p;
    if (l < 77)      p = vtxt + (size_t)(b * 77 + l) * N_C + h * N_D + d;
    else if (l < 81) p = vimg + (size_t)(b * 4 + l - 77) * N_C + h * N_D + d;
    else             p = vlbl + (size_t)(b * 4 + l - 81) * N_C + h * N_D + d;
    int slot = (l < 77) ? l : l + 3;
    Vt[d * PSTR + slot] = *p;
  }
  __syncthreads();

  f32x4 sacc[2][6] = {};
#pragma unroll
  for (int ks = 0; ks < 2; ks++) {
    bf16x8 aq[2], bk[6];
#pragma unroll
    for (int m = 0; m < 2; m++)
      aq[m] = *(bf16x8*)&Qs[(w * 32 + m * 16 + c) * QSTR + ks * 32 + g * 8];
#pragma unroll
    for (int n = 0; n < 6; n++)
      bk[n] = *(bf16x8*)&Ks[(n * 16 + c) * QSTR + ks * 32 + g * 8];
#pragma unroll
    for (int m = 0; m < 2; m++)
#pragma unroll
      for (int n = 0; n < 6; n++)
        sacc[m][n] = __builtin_amdgcn_mfma_f32_16x16x32_bf16(aq[m], bk[n], sacc[m][n], 0, 0, 0);
  }
  __syncthreads();

  const float NEG = -1e30f;
#pragma unroll
  for (int m = 0; m < 2; m++) {
#pragma unroll
    for (int j = 0; j < 4; j++) {
      float tmax = NEG;
#pragma unroll
      for (int n = 0; n < 5; n++)
        if (n * 16 + c < 77) tmax = fmaxf(tmax, sacc[m][n][j]);
#pragma unroll
      for (int off = 1; off < 16; off <<= 1) tmax = fmaxf(tmax, __shfl_xor(tmax, off));
      float pv[5], tsum = 0.f;
#pragma unroll
      for (int n = 0; n < 5; n++) {
        float v = (n * 16 + c < 77) ? __expf(sacc[m][n][j] - tmax) : 0.f;
        pv[n] = v; tsum += v;
      }
#pragma unroll
      for (int off = 1; off < 16; off <<= 1) tsum += __shfl_xor(tsum, off);
      float v5 = sacc[m][5][j];
      float imax = (c < 4) ? v5 : NEG;
#pragma unroll
      for (int off = 1; off < 16; off <<= 1) imax = fmaxf(imax, __shfl_xor(imax, off));
      float ie = (c < 4) ? __expf(v5 - imax) : 0.f, isum = ie;
#pragma unroll
      for (int off = 1; off < 16; off <<= 1) isum += __shfl_xor(isum, off);
      float lmax = (c >= 4 && c < 8) ? v5 : NEG;
#pragma unroll
      for (int off = 1; off < 16; off <<= 1) lmax = fmaxf(lmax, __shfl_xor(lmax, off));
      float le = (c >= 4 && c < 8) ? __expf(v5 - lmax) : 0.f, lsum = le;
#pragma unroll
      for (int off = 1; off < 16; off <<= 1) lsum += __shfl_xor(lsum, off);

      float rt = 1.f / tsum;
      float p5 = (c < 4) ? ie / isum : ((c < 8) ? le / lsum : 0.f);
      int rowl = w * 32 + m * 16 + g * 4 + j;
#pragma unroll
      for (int n = 0; n < 5; n++)
        Ps[rowl * PSTR + n * 16 + c] = f2b(pv[n] * rt);
      Ps[rowl * PSTR + 80 + c] = f2b(p5);
    }
  }
  __syncthreads();

  f32x4 oacc[2][4] = {};
#pragma unroll
  for (int ks = 0; ks < 3; ks++) {
    bf16x8 ap[2], bv[4];
#pragma unroll
    for (int m = 0; m < 2; m++)
      ap[m] = *(bf16x8*)&Ps[(w * 32 + m * 16 + c) * PSTR + ks * 32 + g * 8];
#pragma unroll
    for (int n = 0; n < 4; n++)
      bv[n] = *(bf16x8*)&Vt[(n * 16 + c) * PSTR + ks * 32 + g * 8];
#pragma unroll
    for (int m = 0; m < 2; m++)
#pragma unroll
      for (int n = 0; n < 4; n++)
        oacc[m][n] = __builtin_amdgcn_mfma_f32_16x16x32_bf16(ap[m], bv[n], oacc[m][n], 0, 0, 0);
  }

#pragma unroll
  for (int m = 0; m < 2; m++) {
    int rbase = w * 32 + m * 16 + g * 4;
#pragma unroll
    for (int n = 0; n < 4; n++) {
      int d = n * 16 + c;
#pragma unroll
      for (int j = 0; j < 4; j++) {
        int s = s0 + rbase + j;
        outa[(size_t)(b * N_S + s) * N_C + h * N_D + d] = f2b(oacc[m][n][j]);
      }
    }
  }
}

extern "C" void kernel_launch(void* const* d_in, const int* in_sizes, int n_in,
                              void* d_out, int out_size, void* d_ws, size_t ws_size,
                              hipStream_t stream) {
  const float* hs   = (const float*)d_in[0];
  const float* enc  = (const float*)d_in[1];
  const float* Wq   = (const float*)d_in[2];
  const float* Wk   = (const float*)d_in[3];
  const float* Wv   = (const float*)d_in[4];
  const float* Wkip = (const float*)d_in[5];
  const float* Wvip = (const float*)d_in[6];
  const float* Wklb = (const float*)d_in[7];
  const float* Wvlb = (const float*)d_in[8];
  const float* Wo   = (const float*)d_in[9];
  const float* bo   = (const float*)d_in[10];

  if (ws_size < 83087360u) return;
  char* ws = (char*)d_ws;
  u16* wq_t   = (u16*)(ws + 0);
  u16* wo_t   = (u16*)(ws + 3276800);
  u16* wk_t   = (u16*)(ws + 6553600);
  u16* wv_t   = (u16*)(ws + 11796480);
  u16* wkip_t = (u16*)(ws + 17039360);
  u16* wvip_t = (u16*)(ws + 22282240);
  u16* wklb_t = (u16*)(ws + 27525120);
  u16* wvlb_t = (u16*)(ws + 32768000);
  u16* etxt   = (u16*)(ws + 38010880);
  u16* eimg   = (u16*)(ws + 39272448);
  u16* elbl   = (u16*)(ws + 39337984);
  u16* ktxt   = (u16*)(ws + 39403520);
  u16* vtxt   = (u16*)(ws + 40192000);
  u16* kimg   = (u16*)(ws + 40980480);
  u16* vimg   = (u16*)(ws + 41021440);
  u16* klbl   = (u16*)(ws + 41062400);
  u16* vlbl   = (u16*)(ws + 41103360);
  u16* attn   = (u16*)(ws + 41144320);
  // d_out (84 MB): lower half = q bf16, upper half = hs bf16; both consumed
  // before the final O-proj overwrites d_out with f32 output.
  u16* qbuf   = (u16*)d_out;
  u16* hsb    = (u16*)d_out + (size_t)N_S * N_B * N_C;

  k_cvt<<<2048, 256, 0, stream>>>(hs, hsb, (N_B * N_S * N_C) / 8);

  TPargs tp;
  tp.s[0] = Wq;   tp.d[0] = wq_t;   tp.K[0] = 1280;
  tp.s[1] = Wo;   tp.d[1] = wo_t;   tp.K[1] = 1280;
  tp.s[2] = Wk;   tp.d[2] = wk_t;   tp.K[2] = 2048;
  tp.s[3] = Wv;   tp.d[3] = wv_t;   tp.K[3] = 2048;
  tp.s[4] = Wkip; tp.d[4] = wkip_t; tp.K[4] = 2048;
  tp.s[5] = Wvip; tp.d[5] = wvip_t; tp.K[5] = 2048;
  tp.s[6] = Wklb; tp.d[6] = wklb_t; tp.K[6] = 2048;
  tp.s[7] = Wvlb; tp.d[7] = wvlb_t; tp.K[7] = 2048;
  k_transpose8<<<dim3(40, 64, 8), dim3(32, 8), 0, stream>>>(tp);

  k_encpack<<<340, 256, 0, stream>>>(enc, etxt, eimg, elbl);

  // Q = hs @ Wq scaled by D^-0.5  (256x320 tiles, grid 256 = 1 full round)
  gemm8p<1><<<256, 512, 0, stream>>>(hsb, wq_t, qbuf, 16384, 1280, 1280,
                                     0.125f, nullptr, nullptr);
  // all 6 KV projections, one launch (prefetched 2-phase)
  kv_gemm<<<dim3(10, 5, 2), 256, 0, stream>>>(etxt, eimg, elbl,
                                              wk_t, wv_t, wkip_t, wvip_t, wklb_t, wvlb_t,
                                              ktxt, vtxt, kimg, vimg, klbl, vlbl);

  attn_kern<<<dim3(32, N_H, N_B), 256, 0, stream>>>(qbuf, ktxt, vtxt, kimg, vimg,
                                                    klbl, vlbl, attn);
  // out = attn @ Wo + bo + hs
  gemm8p<2><<<256, 512, 0, stream>>>(attn, wo_t, d_out, 16384, 1280, 1280,
                                     1.f, bo, hs);
}

// Round 8
// 280.724 us; speedup vs baseline: 1.1446x; 1.1446x over previous
//
#include <hip/hip_runtime.h>
#include <hip/hip_bf16.h>

typedef unsigned short u16;
using f32x4  = __attribute__((ext_vector_type(4))) float;
using bf16x8 = __attribute__((ext_vector_type(8))) short;

#define N_B 4
#define N_S 4096
#define N_C 1280
#define N_DC 2048
#define N_H 20
#define N_D 64

__device__ __forceinline__ u16 f2b(float f) {
  union { float f; unsigned u; } x; x.f = f;
  return (u16)((x.u + 0x7fffu + ((x.u >> 16) & 1u)) >> 16);
}

__device__ __forceinline__ void gld16(const u16* g, u16* l) {
  __builtin_amdgcn_global_load_lds(
      (const __attribute__((address_space(1))) unsigned int*)(g),
      (__attribute__((address_space(3))) unsigned int*)(l), 16, 0, 0);
}

// ---------- hs f32 -> bf16
__global__ void k_cvt(const float* __restrict__ src, u16* __restrict__ dst, int n8) {
  for (int i = blockIdx.x * 256 + threadIdx.x; i < n8; i += gridDim.x * 256) {
    const float4 v0 = *(const float4*)(src + (size_t)i * 8);
    const float4 v1 = *(const float4*)(src + (size_t)i * 8 + 4);
    alignas(16) u16 t[8];
    t[0] = f2b(v0.x); t[1] = f2b(v0.y); t[2] = f2b(v0.z); t[3] = f2b(v0.w);
    t[4] = f2b(v1.x); t[5] = f2b(v1.y); t[6] = f2b(v1.z); t[7] = f2b(v1.w);
    *(uint4*)(dst + (size_t)i * 8) = *(uint4*)t;
  }
}

// ---------- batched weight transpose + bf16
struct TPargs { const float* s[8]; u16* d[8]; int K[8]; };

__global__ void k_transpose8(TPargs a) {
  int z = blockIdx.z;
  const float* __restrict__ src = a.s[z];
  u16* __restrict__ dst = a.d[z];
  int K = a.K[z];
  int k0 = blockIdx.y * 32;
  if (k0 >= K) return;
  __shared__ float tl[32][33];
  int n0 = blockIdx.x * 32;
  int tx = threadIdx.x, ty = threadIdx.y;
#pragma unroll
  for (int j = 0; j < 32; j += 8)
    tl[ty + j][tx] = src[(size_t)(k0 + ty + j) * N_C + (n0 + tx)];
  __syncthreads();
#pragma unroll
  for (int j = 0; j < 32; j += 8)
    dst[(size_t)(n0 + ty + j) * K + (k0 + tx)] = f2b(tl[tx][ty + j]);
}

// ---------- pack encoder rows
__global__ void k_encpack(const float* __restrict__ enc, u16* __restrict__ txt,
                          u16* __restrict__ img, u16* __restrict__ lbl) {
  int row = blockIdx.x;
  int b = row / 85, l = row % 85;
  const float* s = enc + (size_t)row * N_DC;
  u16* d;
  if (l < 77)      d = txt + (size_t)(b * 77 + l) * N_DC;
  else if (l < 81) d = img + (size_t)(b * 4 + (l - 77)) * N_DC;
  else             d = lbl + (size_t)(b * 4 + (l - 81)) * N_DC;
  for (int i = threadIdx.x; i < N_DC; i += 256) d[i] = f2b(s[i]);
}

// ================= 256x320 GEMM, dbuf, COUNTED vmcnt (T4) =================
// C[M x N] = A[M x K](bf16) * Bt[N x K]^T.  512 thr = 8 waves (2M x 4N),
// wave tile 128x80, BK=64.
// LDS (u16): A0 [0,16384) A1 [16384,32768) B0 [32768,53248) B1 [53248,73728).
// Per tile t: issue stage(t+1) [4 A + 5 B gld]; s_waitcnt vmcnt(9) (drains
// tile t's 9 loads issued one tile earlier, leaves the new 9 in flight);
// BARR (makes all waves' DMA visible); compute; BARR (protects buffers
// re-staged next tile). Last tile: vmcnt(0). Never a full drain mid-loop.
// Grid = (M/256)*(N/320) = 256 = one full round on 256 CUs.
// EPI: 1 = bf16 store * scale, 2 = f32 store + bias + resid

__device__ __forceinline__ void stage64(const u16* __restrict__ g, int ldK,
                                        int row0, int kk, u16* ldsb,
                                        int w, int lane) {
  int r = w * 8 + (lane >> 3);
  int gslot = ((lane & 7) ^ (lane >> 3)) << 3;
  gld16(g + (size_t)(row0 + r) * ldK + kk + gslot, ldsb + w * 512);
}
__device__ __forceinline__ void stageA4(const u16* Ag, int K, int kk, u16* ldsb,
                                        int w, int lane) {
#pragma unroll
  for (int j = 0; j < 4; j++)
    stage64(Ag, K, j * 64, kk, ldsb + j * 4096, w, lane);
}
__device__ __forceinline__ void stageB5(const u16* Bg, int K, int kk, u16* ldsb,
                                        int w, int lane) {
#pragma unroll
  for (int j = 0; j < 5; j++)
    stage64(Bg, K, j * 64, kk, ldsb + j * 4096, w, lane);
}

#define RD_A2(aoff, mh)                                                      \
  _Pragma("unroll") for (int mi = 0; mi < 2; mi++) {                         \
    _Pragma("unroll") for (int ks = 0; ks < 2; ks++) {                       \
      int row = wr * 128 + ((mh) * 2 + mi) * 16 + lrow;                      \
      int slot = (ks * 4 + g) ^ (lane & 7);                                  \
      af[mi][ks] = *(const bf16x8*)&lds[(aoff) + row * 64 + slot * 8];       \
    }                                                                        \
  }

#define RD_B5(boff)                                                          \
  _Pragma("unroll") for (int n = 0; n < 5; n++) {                            \
    _Pragma("unroll") for (int ks = 0; ks < 2; ks++) {                       \
      int row = wc * 80 + n * 16 + lrow;                                     \
      int slot = (ks * 4 + g) ^ (lane & 7);                                  \
      bf[n][ks] = *(const bf16x8*)&lds[(boff) + row * 64 + slot * 8];        \
    }                                                                        \
  }

#define MFMA20(mh)                                                           \
  _Pragma("unroll") for (int mi = 0; mi < 2; mi++) {                         \
    _Pragma("unroll") for (int n = 0; n < 5; n++) {                          \
      _Pragma("unroll") for (int ks = 0; ks < 2; ks++)                       \
        acc[(mh) * 2 + mi][n] = __builtin_amdgcn_mfma_f32_16x16x32_bf16(     \
            af[mi][ks], bf[n][ks], acc[(mh) * 2 + mi][n], 0, 0, 0);          \
    }                                                                        \
  }

#define BARR()  __builtin_amdgcn_s_barrier()
#define VM9()   asm volatile("s_waitcnt vmcnt(9)" ::: "memory")
#define VM8()   asm volatile("s_waitcnt vmcnt(8)" ::: "memory")
#define VM0()   asm volatile("s_waitcnt vmcnt(0)" ::: "memory")
#define PRIO(x) __builtin_amdgcn_s_setprio(x)

template<int EPI>
__global__ __launch_bounds__(512, 1)
void gemm8p(const u16* __restrict__ A, const u16* __restrict__ Bt,
            void* __restrict__ Cv, int M, int N, int K, float scale,
            const float* __restrict__ bias, const float* __restrict__ resid) {
  __shared__ __align__(16) u16 lds[73728];
  const int t = threadIdx.x, lane = t & 63, w = t >> 6;
  const int wr = w >> 2, wc = w & 3;
  const int lrow = lane & 15, g = lane >> 4;

  int nt = N / 320;
  int nwg = gridDim.x, bid = blockIdx.x;
  int swz = ((nwg & 7) == 0) ? ((bid & 7) * (nwg >> 3) + (bid >> 3)) : bid;
  int bm = swz / nt, bn = swz % nt;

  const u16* Ag = A  + (size_t)bm * 256 * K;
  const u16* Bg = Bt + (size_t)bn * 320 * K;
  const int NT = K >> 6;

  f32x4 acc[8][5] = {};
  bf16x8 af[2][2], bf[5][2];

  // prologue: stage tile0 -> buf0 (B first, then A: matches steady-state order)
  stageB5(Bg, K, 0, lds + 32768, w, lane);
  stageA4(Ag, K, 0, lds + 0,     w, lane);

  for (int tt = 0; tt < NT; ++tt) {
    int c = tt & 1;
    int aof  = c * 16384,        bof  = 32768 + c * 20480;
    int aof1 = (c ^ 1) * 16384,  bof1 = 32768 + (c ^ 1) * 20480;
    // issue next tile's 9 staging loads (targets buffers whose readers
    // finished at the previous tile's closing barrier)
    if (tt + 1 < NT) {
      stageB5(Bg, K, (tt + 1) * 64, lds + bof1, w, lane);
      stageA4(Ag, K, (tt + 1) * 64, lds + aof1, w, lane);
      VM9();           // drain tile tt's 9 loads; keep the new 9 in flight
    } else {
      VM0();           // last tile: everything needed must be in
    }
    BARR();            // all waves' DMA for tile tt now visible
    // compute tile tt from buf c
    RD_B5(bof);
    RD_A2(aof, 0);
    PRIO(1); MFMA20(0); PRIO(0);
    RD_A2(aof, 1);
    PRIO(1); MFMA20(1); PRIO(0);
    RD_A2(aof, 2);
    PRIO(1); MFMA20(2); PRIO(0);
    RD_A2(aof, 3);
    PRIO(1); MFMA20(3); PRIO(0);
    BARR();            // readers of buf c done -> next tile may restage it
  }

  // epilogue
#pragma unroll
  for (int m = 0; m < 8; m++) {
    int row = bm * 256 + wr * 128 + m * 16 + g * 4;
#pragma unroll
    for (int n = 0; n < 5; n++) {
      int col = bn * 320 + wc * 80 + n * 16 + lrow;
#pragma unroll
      for (int j = 0; j < 4; j++) {
        float v = acc[m][n][j];
        if constexpr (EPI == 1)
          ((u16*)Cv)[(size_t)(row + j) * N + col] = f2b(v * scale);
        else
          ((float*)Cv)[(size_t)(row + j) * N + col] =
              v + bias[col] + resid[(size_t)(row + j) * N + col];
      }
    }
  }
}

// ---------- all 6 KV projections in one launch, counted-vmcnt dbuf
__global__ __launch_bounds__(256, 2)
void kv_gemm(const u16* __restrict__ etxt, const u16* __restrict__ eimg, const u16* __restrict__ elbl,
             const u16* __restrict__ wk,   const u16* __restrict__ wv,
             const u16* __restrict__ wkip, const u16* __restrict__ wvip,
             const u16* __restrict__ wklb, const u16* __restrict__ wvlb,
             u16* ktxt, u16* vtxt, u16* kimg, u16* vimg, u16* klbl, u16* vlbl) {
  __shared__ __align__(16) u16 lds[2][2][8192];   // [buf][A/B][128*64]
  int bn = blockIdx.x, my = blockIdx.y, kv = blockIdx.z;
  const u16 *A, *Bt; u16* C; int M, bm;
  if (my < 3)       { A = etxt; M = 308; bm = my; Bt = kv ? wv   : wk;   C = kv ? vtxt : ktxt; }
  else if (my == 3) { A = eimg; M = 16;  bm = 0;  Bt = kv ? wvip : wkip; C = kv ? vimg : kimg; }
  else              { A = elbl; M = 16;  bm = 0;  Bt = kv ? wvlb : wklb; C = kv ? vlbl : klbl; }
  const int K = 2048;
  int t = threadIdx.x, lane = t & 63, w = t >> 6;
  int wm = w >> 1, wn = w & 1;
  int c8 = lane & 7, rsub = lane >> 3;

  f32x4 acc[4][4] = {};

#define KVSTAGE(kt, buf)                                                      \
  {                                                                           \
    int k0 = (kt) * 64;                                                       \
    _Pragma("unroll") for (int i2 = 0; i2 < 4; i2++) {                        \
      int rloc = w * 32 + i2 * 8;                                             \
      int ra = bm * 128 + rloc + rsub; if (ra >= M) ra = M - 1;               \
      int rb = bn * 128 + rloc + rsub;                                        \
      gld16(A  + (size_t)ra * K + k0 + c8 * 8, &lds[buf][0][rloc * 64]);      \
      gld16(Bt + (size_t)rb * K + k0 + c8 * 8, &lds[buf][1][rloc * 64]);      \
    }                                                                         \
  }

  KVSTAGE(0, 0);
  int cur = 0;
  for (int kt = 0; kt < 32; kt++) {
    if (kt < 31) { KVSTAGE(kt + 1, cur ^ 1); VM8(); }
    else VM0();
    __syncthreads();
#pragma unroll
    for (int ks = 0; ks < 2; ks++) {
      bf16x8 afr[4], bfr[4];
#pragma unroll
      for (int m = 0; m < 4; m++)
        afr[m] = *(bf16x8*)&lds[cur][0][(wm * 64 + m * 16 + (lane & 15)) * 64 + ks * 32 + (lane >> 4) * 8];
#pragma unroll
      for (int n = 0; n < 4; n++)
        bfr[n] = *(bf16x8*)&lds[cur][1][(wn * 64 + n * 16 + (lane & 15)) * 64 + ks * 32 + (lane >> 4) * 8];
#pragma unroll
      for (int m = 0; m < 4; m++)
#pragma unroll
        for (int n = 0; n < 4; n++)
          acc[m][n] = __builtin_amdgcn_mfma_f32_16x16x32_bf16(afr[m], bfr[n], acc[m][n], 0, 0, 0);
    }
    __syncthreads();
    cur ^= 1;
  }
#undef KVSTAGE

#pragma unroll
  for (int m = 0; m < 4; m++) {
    int row = bm * 128 + wm * 64 + m * 16 + ((lane >> 4) << 2);
#pragma unroll
    for (int n = 0; n < 4; n++) {
      int col = bn * 128 + wn * 64 + n * 16 + (lane & 15);
#pragma unroll
      for (int j = 0; j < 4; j++) {
        int r = row + j;
        if (r >= M) continue;
        ((u16*)C)[(size_t)r * 1280 + col] = f2b(acc[m][n][j]);
      }
    }
  }
}

// ---------- fused attention (unchanged)
#define QSTR 72
#define PSTR 104

__global__ __launch_bounds__(256, 2)
void attn_kern(const u16* __restrict__ q,
               const u16* __restrict__ ktxt, const u16* __restrict__ vtxt,
               const u16* __restrict__ kimg, const u16* __restrict__ vimg,
               const u16* __restrict__ klbl, const u16* __restrict__ vlbl,
               u16* __restrict__ outa) {
  __shared__ __align__(16) char smem[45568];
  u16* Qs = (u16*)smem;
  u16* Ks = (u16*)(smem + 18432);
  u16* Ps = (u16*)smem;
  u16* Vt = (u16*)(smem + 32256);

  int st = blockIdx.x, h = blockIdx.y, b = blockIdx.z;
  int t = threadIdx.x, lane = t & 63, w = t >> 6;
  int s0 = st * 128;
  int c = lane & 15, g = lane >> 4;

  for (int i = t; i < 27136 / 16; i += 256)
    ((uint4*)(smem + 18432))[i] = make_uint4(0, 0, 0, 0);
#pragma unroll
  for (int i = 0; i < 4; i++) {
    int cid = t + i * 256; int r = cid >> 3, c8 = cid & 7;
    *(uint4*)&Qs[r * QSTR + c8 * 8] =
        *(const uint4*)(q + (size_t)(b * N_S + s0 + r) * N_C + h * N_D + c8 * 8);
  }
  __syncthreads();
  for (int cid = t; cid < 680; cid += 256) {
    int l = cid >> 3, c8 = cid & 7;
    const u16* p;
    if (l < 77)      p = ktxt + (size_t)(b * 77 + l) * N_C + h * N_D + c8 * 8;
    else if (l < 81) p = kimg + (size_t)(b * 4 + l - 77) * N_C + h * N_D + c8 * 8;
    else             p = klbl + (size_t)(b * 4 + l - 81) * N_C + h * N_D + c8 * 8;
    int row = (l < 77) ? l : l + 3;
    *(uint4*)&Ks[row * QSTR + c8 * 8] = *(const uint4*)p;
  }
  for (int e = t; e < 85 * 64; e += 256) {
    int l = e >> 6, d = e & 63;
    const u16* p;
    if (l < 77)      p = vtxt + (size_t)(b * 77 + l) * N_C + h * N_D + d;
    else if (l < 81) p = vimg + (size_t)(b * 4 + l - 77) * N_C + h * N_D + d;
    else             p = vlbl + (size_t)(b * 4 + l - 81) * N_C + h * N_D + d;
    int slot = (l < 77) ? l : l + 3;
    Vt[d * PSTR + slot] = *p;
  }
  __syncthreads();

  f32x4 sacc[2][6] = {};
#pragma unroll
  for (int ks = 0; ks < 2; ks++) {
    bf16x8 aq[2], bk[6];
#pragma unroll
    for (int m = 0; m < 2; m++)
      aq[m] = *(bf16x8*)&Qs[(w * 32 + m * 16 + c) * QSTR + ks * 32 + g * 8];
#pragma unroll
    for (int n = 0; n < 6; n++)
      bk[n] = *(bf16x8*)&Ks[(n * 16 + c) * QSTR + ks * 32 + g * 8];
#pragma unroll
    for (int m = 0; m < 2; m++)
#pragma unroll
      for (int n = 0; n < 6; n++)
        sacc[m][n] = __builtin_amdgcn_mfma_f32_16x16x32_bf16(aq[m], bk[n], sacc[m][n], 0, 0, 0);
  }
  __syncthreads();

  const float NEG = -1e30f;
#pragma unroll
  for (int m = 0; m < 2; m++) {
#pragma unroll
    for (int j = 0; j < 4; j++) {
      float tmax = NEG;
#pragma unroll
      for (int n = 0; n < 5; n++)
        if (n * 16 + c < 77) tmax = fmaxf(tmax, sacc[m][n][j]);
#pragma unroll
      for (int off = 1; off < 16; off <<= 1) tmax = fmaxf(tmax, __shfl_xor(tmax, off));
      float pv[5], tsum = 0.f;
#pragma unroll
      for (int n = 0; n < 5; n++) {
        float v = (n * 16 + c < 77) ? __expf(sacc[m][n][j] - tmax) : 0.f;
        pv[n] = v; tsum += v;
      }
#pragma unroll
      for (int off = 1; off < 16; off <<= 1) tsum += __shfl_xor(tsum, off);
      float v5 = sacc[m][5][j];
      float imax = (c < 4) ? v5 : NEG;
#pragma unroll
      for (int off = 1; off < 16; off <<= 1) imax = fmaxf(imax, __shfl_xor(imax, off));
      float ie = (c < 4) ? __expf(v5 - imax) : 0.f, isum = ie;
#pragma unroll
      for (int off = 1; off < 16; off <<= 1) isum += __shfl_xor(isum, off);
      float lmax = (c >= 4 && c < 8) ? v5 : NEG;
#pragma unroll
      for (int off = 1; off < 16; off <<= 1) lmax = fmaxf(lmax, __shfl_xor(lmax, off));
      float le = (c >= 4 && c < 8) ? __expf(v5 - lmax) : 0.f, lsum = le;
#pragma unroll
      for (int off = 1; off < 16; off <<= 1) lsum += __shfl_xor(lsum, off);

      float rt = 1.f / tsum;
      float p5 = (c < 4) ? ie / isum : ((c < 8) ? le / lsum : 0.f);
      int rowl = w * 32 + m * 16 + g * 4 + j;
#pragma unroll
      for (int n = 0; n < 5; n++)
        Ps[rowl * PSTR + n * 16 + c] = f2b(pv[n] * rt);
      Ps[rowl * PSTR + 80 + c] = f2b(p5);
    }
  }
  __syncthreads();

  f32x4 oacc[2][4] = {};
#pragma unroll
  for (int ks = 0; ks < 3; ks++) {
    bf16x8 ap[2], bv[4];
#pragma unroll
    for (int m = 0; m < 2; m++)
      ap[m] = *(bf16x8*)&Ps[(w * 32 + m * 16 + c) * PSTR + ks * 32 + g * 8];
#pragma unroll
    for (int n = 0; n < 4; n++)
      bv[n] = *(bf16x8*)&Vt[(n * 16 + c) * PSTR + ks * 32 + g * 8];
#pragma unroll
    for (int m = 0; m < 2; m++)
#pragma unroll
      for (int n = 0; n < 4; n++)
        oacc[m][n] = __builtin_amdgcn_mfma_f32_16x16x32_bf16(ap[m], bv[n], oacc[m][n], 0, 0, 0);
  }

#pragma unroll
  for (int m = 0; m < 2; m++) {
    int rbase = w * 32 + m * 16 + g * 4;
#pragma unroll
    for (int n = 0; n < 4; n++) {
      int d = n * 16 + c;
#pragma unroll
      for (int j = 0; j < 4; j++) {
        int s = s0 + rbase + j;
        outa[(size_t)(b * N_S + s) * N_C + h * N_D + d] = f2b(oacc[m][n][j]);
      }
    }
  }
}

extern "C" void kernel_launch(void* const* d_in, const int* in_sizes, int n_in,
                              void* d_out, int out_size, void* d_ws, size_t ws_size,
                              hipStream_t stream) {
  const float* hs   = (const float*)d_in[0];
  const float* enc  = (const float*)d_in[1];
  const float* Wq   = (const float*)d_in[2];
  const float* Wk   = (const float*)d_in[3];
  const float* Wv   = (const float*)d_in[4];
  const float* Wkip = (const float*)d_in[5];
  const float* Wvip = (const float*)d_in[6];
  const float* Wklb = (const float*)d_in[7];
  const float* Wvlb = (const float*)d_in[8];
  const float* Wo   = (const float*)d_in[9];
  const float* bo   = (const float*)d_in[10];

  if (ws_size < 83087360u) return;
  char* ws = (char*)d_ws;
  u16* wq_t   = (u16*)(ws + 0);
  u16* wo_t   = (u16*)(ws + 3276800);
  u16* wk_t   = (u16*)(ws + 6553600);
  u16* wv_t   = (u16*)(ws + 11796480);
  u16* wkip_t = (u16*)(ws + 17039360);
  u16* wvip_t = (u16*)(ws + 22282240);
  u16* wklb_t = (u16*)(ws + 27525120);
  u16* wvlb_t = (u16*)(ws + 32768000);
  u16* etxt   = (u16*)(ws + 38010880);
  u16* eimg   = (u16*)(ws + 39272448);
  u16* elbl   = (u16*)(ws + 39337984);
  u16* ktxt   = (u16*)(ws + 39403520);
  u16* vtxt   = (u16*)(ws + 40192000);
  u16* kimg   = (u16*)(ws + 40980480);
  u16* vimg   = (u16*)(ws + 41021440);
  u16* klbl   = (u16*)(ws + 41062400);
  u16* vlbl   = (u16*)(ws + 41103360);
  u16* attn   = (u16*)(ws + 41144320);
  // d_out (84 MB): lower half = q bf16, upper half = hs bf16; both consumed
  // before the final O-proj overwrites d_out with f32 output.
  u16* qbuf   = (u16*)d_out;
  u16* hsb    = (u16*)d_out + (size_t)N_S * N_B * N_C;

  k_cvt<<<2048, 256, 0, stream>>>(hs, hsb, (N_B * N_S * N_C) / 8);

  TPargs tp;
  tp.s[0] = Wq;   tp.d[0] = wq_t;   tp.K[0] = 1280;
  tp.s[1] = Wo;   tp.d[1] = wo_t;   tp.K[1] = 1280;
  tp.s[2] = Wk;   tp.d[2] = wk_t;   tp.K[2] = 2048;
  tp.s[3] = Wv;   tp.d[3] = wv_t;   tp.K[3] = 2048;
  tp.s[4] = Wkip; tp.d[4] = wkip_t; tp.K[4] = 2048;
  tp.s[5] = Wvip; tp.d[5] = wvip_t; tp.K[5] = 2048;
  tp.s[6] = Wklb; tp.d[6] = wklb_t; tp.K[6] = 2048;
  tp.s[7] = Wvlb; tp.d[7] = wvlb_t; tp.K[7] = 2048;
  k_transpose8<<<dim3(40, 64, 8), dim3(32, 8), 0, stream>>>(tp);

  k_encpack<<<340, 256, 0, stream>>>(enc, etxt, eimg, elbl);

  // Q = hs @ Wq scaled by D^-0.5  (256x320 tiles, grid 256 = 1 full round)
  gemm8p<1><<<256, 512, 0, stream>>>(hsb, wq_t, qbuf, 16384, 1280, 1280,
                                     0.125f, nullptr, nullptr);
  // all 6 KV projections, one launch (counted-vmcnt dbuf)
  kv_gemm<<<dim3(10, 5, 2), 256, 0, stream>>>(etxt, eimg, elbl,
                                              wk_t, wv_t, wkip_t, wvip_t, wklb_t, wvlb_t,
                                              ktxt, vtxt, kimg, vimg, klbl, vlbl);

  attn_kern<<<dim3(32, N_H, N_B), 256, 0, stream>>>(qbuf, ktxt, vtxt, kimg, vimg,
                                                    klbl, vlbl, attn);
  // out = attn @ Wo + bo + hs
  gemm8p<2><<<256, 512, 0, stream>>>(attn, wo_t, d_out, 16384, 1280, 1280,
                                     1.f, bo, hs);
}

// Round 10
// 257.170 us; speedup vs baseline: 1.2494x; 1.0916x over previous
//
#include <hip/hip_runtime.h>
#include <hip/hip_bf16.h>

typedef unsigned short u16;
using f32x4  = __attribute__((ext_vector_type(4))) float;
using bf16x8 = __attribute__((ext_vector_type(8))) short;

#define N_B 4
#define N_S 4096
#define N_C 1280
#define N_DC 2048
#define N_H 20
#define N_D 64

__device__ __forceinline__ u16 f2b(float f) {
  union { float f; unsigned u; } x; x.f = f;
  return (u16)((x.u + 0x7fffu + ((x.u >> 16) & 1u)) >> 16);
}

__device__ __forceinline__ void gld16(const u16* g, u16* l) {
  __builtin_amdgcn_global_load_lds(
      (const __attribute__((address_space(1))) unsigned int*)(g),
      (__attribute__((address_space(3))) unsigned int*)(l), 16, 0, 0);
}

// ---------- hs f32 -> bf16
__global__ void k_cvt(const float* __restrict__ src, u16* __restrict__ dst, int n8) {
  for (int i = blockIdx.x * 256 + threadIdx.x; i < n8; i += gridDim.x * 256) {
    const float4 v0 = *(const float4*)(src + (size_t)i * 8);
    const float4 v1 = *(const float4*)(src + (size_t)i * 8 + 4);
    alignas(16) u16 t[8];
    t[0] = f2b(v0.x); t[1] = f2b(v0.y); t[2] = f2b(v0.z); t[3] = f2b(v0.w);
    t[4] = f2b(v1.x); t[5] = f2b(v1.y); t[6] = f2b(v1.z); t[7] = f2b(v1.w);
    *(uint4*)(dst + (size_t)i * 8) = *(uint4*)t;
  }
}

// ---------- batched weight transpose + bf16
struct TPargs { const float* s[8]; u16* d[8]; int K[8]; };

__global__ void k_transpose8(TPargs a) {
  int z = blockIdx.z;
  const float* __restrict__ src = a.s[z];
  u16* __restrict__ dst = a.d[z];
  int K = a.K[z];
  int k0 = blockIdx.y * 32;
  if (k0 >= K) return;
  __shared__ float tl[32][33];
  int n0 = blockIdx.x * 32;
  int tx = threadIdx.x, ty = threadIdx.y;
#pragma unroll
  for (int j = 0; j < 32; j += 8)
    tl[ty + j][tx] = src[(size_t)(k0 + ty + j) * N_C + (n0 + tx)];
  __syncthreads();
#pragma unroll
  for (int j = 0; j < 32; j += 8)
    dst[(size_t)(n0 + ty + j) * K + (k0 + tx)] = f2b(tl[tx][ty + j]);
}

// ---------- pack encoder rows
__global__ void k_encpack(const float* __restrict__ enc, u16* __restrict__ txt,
                          u16* __restrict__ img, u16* __restrict__ lbl) {
  int row = blockIdx.x;
  int b = row / 85, l = row % 85;
  const float* s = enc + (size_t)row * N_DC;
  u16* d;
  if (l < 77)      d = txt + (size_t)(b * 77 + l) * N_DC;
  else if (l < 81) d = img + (size_t)(b * 4 + (l - 77)) * N_DC;
  else             d = lbl + (size_t)(b * 4 + (l - 81)) * N_DC;
  for (int i = threadIdx.x; i < N_DC; i += 256) d[i] = f2b(s[i]);
}

// ================= 256x320 GEMM, double-buffered, 1 barrier/K-tile ========
// Identical to the round-6 structure (best measured) EXCEPT: the MFMA
// cluster is ordered ks-OUTERMOST, so consecutive MFMAs hit 10 distinct
// accumulators (dependency distance 10 instead of 1). Theory: the uniform
// ~2.3 TF/CU ceiling across schedule variants is matrix-pipe dependency
// latency exposed by back-to-back dependent MFMA pairs at 2 waves/SIMD.
// EPI: 1 = bf16 store * scale, 2 = f32 store + bias + resid

__device__ __forceinline__ void stage64(const u16* __restrict__ g, int ldK,
                                        int row0, int kk, u16* ldsb,
                                        int w, int lane) {
  int r = w * 8 + (lane >> 3);
  int gslot = ((lane & 7) ^ (lane >> 3)) << 3;
  gld16(g + (size_t)(row0 + r) * ldK + kk + gslot, ldsb + w * 512);
}
__device__ __forceinline__ void stageA4(const u16* Ag, int K, int kk, u16* ldsb,
                                        int w, int lane) {
#pragma unroll
  for (int j = 0; j < 4; j++)
    stage64(Ag, K, j * 64, kk, ldsb + j * 4096, w, lane);
}
__device__ __forceinline__ void stageB5(const u16* Bg, int K, int kk, u16* ldsb,
                                        int w, int lane) {
#pragma unroll
  for (int j = 0; j < 5; j++)
    stage64(Bg, K, j * 64, kk, ldsb + j * 4096, w, lane);
}

#define RD_A2(aoff, mh)                                                      \
  _Pragma("unroll") for (int mi = 0; mi < 2; mi++) {                         \
    _Pragma("unroll") for (int ks = 0; ks < 2; ks++) {                       \
      int row = wr * 128 + ((mh) * 2 + mi) * 16 + lrow;                      \
      int slot = (ks * 4 + g) ^ (lane & 7);                                  \
      af[mi][ks] = *(const bf16x8*)&lds[(aoff) + row * 64 + slot * 8];       \
    }                                                                        \
  }

#define RD_B5(boff)                                                          \
  _Pragma("unroll") for (int n = 0; n < 5; n++) {                            \
    _Pragma("unroll") for (int ks = 0; ks < 2; ks++) {                       \
      int row = wc * 80 + n * 16 + lrow;                                     \
      int slot = (ks * 4 + g) ^ (lane & 7);                                  \
      bf[n][ks] = *(const bf16x8*)&lds[(boff) + row * 64 + slot * 8];        \
    }                                                                        \
  }

// ks OUTER: 10 independent MFMAs between dependent updates of the same acc
#define MFMA20(mh)                                                           \
  _Pragma("unroll") for (int ks = 0; ks < 2; ks++) {                         \
    _Pragma("unroll") for (int mi = 0; mi < 2; mi++) {                       \
      _Pragma("unroll") for (int n = 0; n < 5; n++)                          \
        acc[(mh) * 2 + mi][n] = __builtin_amdgcn_mfma_f32_16x16x32_bf16(     \
            af[mi][ks], bf[n][ks], acc[(mh) * 2 + mi][n], 0, 0, 0);          \
    }                                                                        \
  }

#define BARR()  __builtin_amdgcn_s_barrier()
#define VM0()   asm volatile("s_waitcnt vmcnt(0)" ::: "memory")
#define PRIO(x) __builtin_amdgcn_s_setprio(x)

template<int EPI>
__global__ __launch_bounds__(512, 1)
void gemm8p(const u16* __restrict__ A, const u16* __restrict__ Bt,
            void* __restrict__ Cv, int M, int N, int K, float scale,
            const float* __restrict__ bias, const float* __restrict__ resid) {
  __shared__ __align__(16) u16 lds[73728];
  const int t = threadIdx.x, lane = t & 63, w = t >> 6;
  const int wr = w >> 2, wc = w & 3;
  const int lrow = lane & 15, g = lane >> 4;

  int nt = N / 320;
  int nwg = gridDim.x, bid = blockIdx.x;
  int swz = ((nwg & 7) == 0) ? ((bid & 7) * (nwg >> 3) + (bid >> 3)) : bid;
  int bm = swz / nt, bn = swz % nt;

  const u16* Ag = A  + (size_t)bm * 256 * K;
  const u16* Bg = Bt + (size_t)bn * 320 * K;
  const int NT = K >> 6;

  f32x4 acc[8][5] = {};
  bf16x8 af[2][2], bf[5][2];

  // prologue: stage tile0 -> buf0
  stageA4(Ag, K, 0, lds + 0,     w, lane);
  stageB5(Bg, K, 0, lds + 32768, w, lane);
  VM0();
  BARR();

  for (int tt = 0; tt < NT; ++tt) {
    int c = tt & 1;
    int aof  = c * 16384,        bof  = 32768 + c * 20480;
    int aof1 = (c ^ 1) * 16384,  bof1 = 32768 + (c ^ 1) * 20480;
    // issue all 9 prefetch loads for tile t+1 first
    if (tt + 1 < NT) {
      stageA4(Ag, K, (tt + 1) * 64, lds + aof1, w, lane);
      stageB5(Bg, K, (tt + 1) * 64, lds + bof1, w, lane);
    }
    // straight-line compute on buf c; compiler manages counted lgkmcnt
    RD_A2(aof, 0); RD_B5(bof);
    PRIO(1); MFMA20(0); PRIO(0);
    RD_A2(aof, 1);
    PRIO(1); MFMA20(1); PRIO(0);
    RD_A2(aof, 2);
    PRIO(1); MFMA20(2); PRIO(0);
    RD_A2(aof, 3);
    PRIO(1); MFMA20(3); PRIO(0);
    // tile boundary: next tile's buf fully staged, all readers of c done
    VM0();
    BARR();
  }

  // epilogue
#pragma unroll
  for (int m = 0; m < 8; m++) {
    int row = bm * 256 + wr * 128 + m * 16 + g * 4;
#pragma unroll
    for (int n = 0; n < 5; n++) {
      int col = bn * 320 + wc * 80 + n * 16 + lrow;
#pragma unroll
      for (int j = 0; j < 4; j++) {
        float v = acc[m][n][j];
        if constexpr (EPI == 1)
          ((u16*)Cv)[(size_t)(row + j) * N + col] = f2b(v * scale);
        else
          ((float*)Cv)[(size_t)(row + j) * N + col] =
              v + bias[col] + resid[(size_t)(row + j) * N + col];
      }
    }
  }
}

// ---------- all 6 KV projections in one launch, prefetched 2-phase
__global__ __launch_bounds__(256, 2)
void kv_gemm(const u16* __restrict__ etxt, const u16* __restrict__ eimg, const u16* __restrict__ elbl,
             const u16* __restrict__ wk,   const u16* __restrict__ wv,
             const u16* __restrict__ wkip, const u16* __restrict__ wvip,
             const u16* __restrict__ wklb, const u16* __restrict__ wvlb,
             u16* ktxt, u16* vtxt, u16* kimg, u16* vimg, u16* klbl, u16* vlbl) {
  __shared__ __align__(16) u16 lds[2][2][8192];   // [buf][A/B][128*64]
  int bn = blockIdx.x, my = blockIdx.y, kv = blockIdx.z;
  const u16 *A, *Bt; u16* C; int M, bm;
  if (my < 3)       { A = etxt; M = 308; bm = my; Bt = kv ? wv   : wk;   C = kv ? vtxt : ktxt; }
  else if (my == 3) { A = eimg; M = 16;  bm = 0;  Bt = kv ? wvip : wkip; C = kv ? vimg : kimg; }
  else              { A = elbl; M = 16;  bm = 0;  Bt = kv ? wvlb : wklb; C = kv ? vlbl : klbl; }
  const int K = 2048;
  int t = threadIdx.x, lane = t & 63, w = t >> 6;
  int wm = w >> 1, wn = w & 1;
  int c8 = lane & 7, rsub = lane >> 3;

  f32x4 acc[4][4] = {};

#define KVSTAGE(kt, buf)                                                      \
  {                                                                           \
    int k0 = (kt) * 64;                                                       \
    _Pragma("unroll") for (int i2 = 0; i2 < 4; i2++) {                        \
      int rloc = w * 32 + i2 * 8;                                             \
      int ra = bm * 128 + rloc + rsub; if (ra >= M) ra = M - 1;               \
      int rb = bn * 128 + rloc + rsub;                                        \
      gld16(A  + (size_t)ra * K + k0 + c8 * 8, &lds[buf][0][rloc * 64]);      \
      gld16(Bt + (size_t)rb * K + k0 + c8 * 8, &lds[buf][1][rloc * 64]);      \
    }                                                                         \
  }

  KVSTAGE(0, 0);
  asm volatile("s_waitcnt vmcnt(0)" ::: "memory");
  __syncthreads();
  int cur = 0;
  for (int kt = 0; kt < 32; kt++) {
    if (kt < 31) KVSTAGE(kt + 1, cur ^ 1);
#pragma unroll
    for (int ks = 0; ks < 2; ks++) {
      bf16x8 afr[4], bfr[4];
#pragma unroll
      for (int m = 0; m < 4; m++)
        afr[m] = *(bf16x8*)&lds[cur][0][(wm * 64 + m * 16 + (lane & 15)) * 64 + ks * 32 + (lane >> 4) * 8];
#pragma unroll
      for (int n = 0; n < 4; n++)
        bfr[n] = *(bf16x8*)&lds[cur][1][(wn * 64 + n * 16 + (lane & 15)) * 64 + ks * 32 + (lane >> 4) * 8];
#pragma unroll
      for (int m = 0; m < 4; m++)
#pragma unroll
        for (int n = 0; n < 4; n++)
          acc[m][n] = __builtin_amdgcn_mfma_f32_16x16x32_bf16(afr[m], bfr[n], acc[m][n], 0, 0, 0);
    }
    asm volatile("s_waitcnt vmcnt(0)" ::: "memory");
    __syncthreads();
    cur ^= 1;
  }
#undef KVSTAGE

#pragma unroll
  for (int m = 0; m < 4; m++) {
    int row = bm * 128 + wm * 64 + m * 16 + ((lane >> 4) << 2);
#pragma unroll
    for (int n = 0; n < 4; n++) {
      int col = bn * 128 + wn * 64 + n * 16 + (lane & 15);
#pragma unroll
      for (int j = 0; j < 4; j++) {
        int r = row + j;
        if (r >= M) continue;
        ((u16*)C)[(size_t)r * 1280 + col] = f2b(acc[m][n][j]);
      }
    }
  }
}

// ---------- fused attention (unchanged)
#define QSTR 72
#define PSTR 104

__global__ __launch_bounds__(256, 2)
void attn_kern(const u16* __restrict__ q,
               const u16* __restrict__ ktxt, const u16* __restrict__ vtxt,
               const u16* __restrict__ kimg, const u16* __restrict__ vimg,
               const u16* __restrict__ klbl, const u16* __restrict__ vlbl,
               u16* __restrict__ outa) {
  __shared__ __align__(16) char smem[45568];
  u16* Qs = (u16*)smem;
  u16* Ks = (u16*)(smem + 18432);
  u16* Ps = (u16*)smem;
  u16* Vt = (u16*)(smem + 32256);

  int st = blockIdx.x, h = blockIdx.y, b = blockIdx.z;
  int t = threadIdx.x, lane = t & 63, w = t >> 6;
  int s0 = st * 128;
  int c = lane & 15, g = lane >> 4;

  for (int i = t; i < 27136 / 16; i += 256)
    ((uint4*)(smem + 18432))[i] = make_uint4(0, 0, 0, 0);
#pragma unroll
  for (int i = 0; i < 4; i++) {
    int cid = t + i * 256; int r = cid >> 3, c8 = cid & 7;
    *(uint4*)&Qs[r * QSTR + c8 * 8] =
        *(const uint4*)(q + (size_t)(b * N_S + s0 + r) * N_C + h * N_D + c8 * 8);
  }
  __syncthreads();
  for (int cid = t; cid < 680; cid += 256) {
    int l = cid >> 3, c8 = cid & 7;
    const u16* p;
    if (l < 77)      p = ktxt + (size_t)(b * 77 + l) * N_C + h * N_D + c8 * 8;
    else if (l < 81) p = kimg + (size_t)(b * 4 + l - 77) * N_C + h * N_D + c8 * 8;
    else             p = klbl + (size_t)(b * 4 + l - 81) * N_C + h * N_D + c8 * 8;
    int row = (l < 77) ? l : l + 3;
    *(uint4*)&Ks[row * QSTR + c8 * 8] = *(const uint4*)p;
  }
  for (int e = t; e < 85 * 64; e += 256) {
    int l = e >> 6, d = e & 63;
    const u16* p;
    if (l < 77)      p = vtxt + (size_t)(b * 77 + l) * N_C + h * N_D + d;
    else if (l < 81) p = vimg + (size_t)(b * 4 + l - 77) * N_C + h * N_D + d;
    else             p = vlbl + (size_t)(b * 4 + l - 81) * N_C + h * N_D + d;
    int slot = (l < 77) ? l : l + 3;
    Vt[d * PSTR + slot] = *p;
  }
  __syncthreads();

  f32x4 sacc[2][6] = {};
#pragma unroll
  for (int ks = 0; ks < 2; ks++) {
    bf16x8 aq[2], bk[6];
#pragma unroll
    for (int m = 0; m < 2; m++)
      aq[m] = *(bf16x8*)&Qs[(w * 32 + m * 16 + c) * QSTR + ks * 32 + g * 8];
#pragma unroll
    for (int n = 0; n < 6; n++)
      bk[n] = *(bf16x8*)&Ks[(n * 16 + c) * QSTR + ks * 32 + g * 8];
#pragma unroll
    for (int m = 0; m < 2; m++)
#pragma unroll
      for (int n = 0; n < 6; n++)
        sacc[m][n] = __builtin_amdgcn_mfma_f32_16x16x32_bf16(aq[m], bk[n], sacc[m][n], 0, 0, 0);
  }
  __syncthreads();

  const float NEG = -1e30f;
#pragma unroll
  for (int m = 0; m < 2; m++) {
#pragma unroll
    for (int j = 0; j < 4; j++) {
      float tmax = NEG;
#pragma unroll
      for (int n = 0; n < 5; n++)
        if (n * 16 + c < 77) tmax = fmaxf(tmax, sacc[m][n][j]);
#pragma unroll
      for (int off = 1; off < 16; off <<= 1) tmax = fmaxf(tmax, __shfl_xor(tmax, off));
      float pv[5], tsum = 0.f;
#pragma unroll
      for (int n = 0; n < 5; n++) {
        float v = (n * 16 + c < 77) ? __expf(sacc[m][n][j] - tmax) : 0.f;
        pv[n] = v; tsum += v;
      }
#pragma unroll
      for (int off = 1; off < 16; off <<= 1) tsum += __shfl_xor(tsum, off);
      float v5 = sacc[m][5][j];
      float imax = (c < 4) ? v5 : NEG;
#pragma unroll
      for (int off = 1; off < 16; off <<= 1) imax = fmaxf(imax, __shfl_xor(imax, off));
      float ie = (c < 4) ? __expf(v5 - imax) : 0.f, isum = ie;
#pragma unroll
      for (int off = 1; off < 16; off <<= 1) isum += __shfl_xor(isum, off);
      float lmax = (c >= 4 && c < 8) ? v5 : NEG;
#pragma unroll
      for (int off = 1; off < 16; off <<= 1) lmax = fmaxf(lmax, __shfl_xor(lmax, off));
      float le = (c >= 4 && c < 8) ? __expf(v5 - lmax) : 0.f, lsum = le;
#pragma unroll
      for (int off = 1; off < 16; off <<= 1) lsum += __shfl_xor(lsum, off);

      float rt = 1.f / tsum;
      float p5 = (c < 4) ? ie / isum : ((c < 8) ? le / lsum : 0.f);
      int rowl = w * 32 + m * 16 + g * 4 + j;
#pragma unroll
      for (int n = 0; n < 5; n++)
        Ps[rowl * PSTR + n * 16 + c] = f2b(pv[n] * rt);
      Ps[rowl * PSTR + 80 + c] = f2b(p5);
    }
  }
  __syncthreads();

  f32x4 oacc[2][4] = {};
#pragma unroll
  for (int ks = 0; ks < 3; ks++) {
    bf16x8 ap[2], bv[4];
#pragma unroll
    for (int m = 0; m < 2; m++)
      ap[m] = *(bf16x8*)&Ps[(w * 32 + m * 16 + c) * PSTR + ks * 32 + g * 8];
#pragma unroll
    for (int n = 0; n < 4; n++)
      bv[n] = *(bf16x8*)&Vt[(n * 16 + c) * PSTR + ks * 32 + g * 8];
#pragma unroll
    for (int m = 0; m < 2; m++)
#pragma unroll
      for (int n = 0; n < 4; n++)
        oacc[m][n] = __builtin_amdgcn_mfma_f32_16x16x32_bf16(ap[m], bv[n], oacc[m][n], 0, 0, 0);
  }

#pragma unroll
  for (int m = 0; m < 2; m++) {
    int rbase = w * 32 + m * 16 + g * 4;
#pragma unroll
    for (int n = 0; n < 4; n++) {
      int d = n * 16 + c;
#pragma unroll
      for (int j = 0; j < 4; j++) {
        int s = s0 + rbase + j;
        outa[(size_t)(b * N_S + s) * N_C + h * N_D + d] = f2b(oacc[m][n][j]);
      }
    }
  }
}

extern "C" void kernel_launch(void* const* d_in, const int* in_sizes, int n_in,
                              void* d_out, int out_size, void* d_ws, size_t ws_size,
                              hipStream_t stream) {
  const float* hs   = (const float*)d_in[0];
  const float* enc  = (const float*)d_in[1];
  const float* Wq   = (const float*)d_in[2];
  const float* Wk   = (const float*)d_in[3];
  const float* Wv   = (const float*)d_in[4];
  const float* Wkip = (const float*)d_in[5];
  const float* Wvip = (const float*)d_in[6];
  const float* Wklb = (const float*)d_in[7];
  const float* Wvlb = (const float*)d_in[8];
  const float* Wo   = (const float*)d_in[9];
  const float* bo   = (const float*)d_in[10];

  if (ws_size < 83087360u) return;
  char* ws = (char*)d_ws;
  u16* wq_t   = (u16*)(ws + 0);
  u16* wo_t   = (u16*)(ws + 3276800);
  u16* wk_t   = (u16*)(ws + 6553600);
  u16* wv_t   = (u16*)(ws + 11796480);
  u16* wkip_t = (u16*)(ws + 17039360);
  u16* wvip_t = (u16*)(ws + 22282240);
  u16* wklb_t = (u16*)(ws + 27525120);
  u16* wvlb_t = (u16*)(ws + 32768000);
  u16* etxt   = (u16*)(ws + 38010880);
  u16* eimg   = (u16*)(ws + 39272448);
  u16* elbl   = (u16*)(ws + 39337984);
  u16* ktxt   = (u16*)(ws + 39403520);
  u16* vtxt   = (u16*)(ws + 40192000);
  u16* kimg   = (u16*)(ws + 40980480);
  u16* vimg   = (u16*)(ws + 41021440);
  u16* klbl   = (u16*)(ws + 41062400);
  u16* vlbl   = (u16*)(ws + 41103360);
  u16* attn   = (u16*)(ws + 41144320);
  // d_out (84 MB): lower half = q bf16, upper half = hs bf16; both consumed
  // before the final O-proj overwrites d_out with f32 output.
  u16* qbuf   = (u16*)d_out;
  u16* hsb    = (u16*)d_out + (size_t)N_S * N_B * N_C;

  k_cvt<<<2048, 256, 0, stream>>>(hs, hsb, (N_B * N_S * N_C) / 8);

  TPargs tp;
  tp.s[0] = Wq;   tp.d[0] = wq_t;   tp.K[0] = 1280;
  tp.s[1] = Wo;   tp.d[1] = wo_t;   tp.K[1] = 1280;
  tp.s[2] = Wk;   tp.d[2] = wk_t;   tp.K[2] = 2048;
  tp.s[3] = Wv;   tp.d[3] = wv_t;   tp.K[3] = 2048;
  tp.s[4] = Wkip; tp.d[4] = wkip_t; tp.K[4] = 2048;
  tp.s[5] = Wvip; tp.d[5] = wvip_t; tp.K[5] = 2048;
  tp.s[6] = Wklb; tp.d[6] = wklb_t; tp.K[6] = 2048;
  tp.s[7] = Wvlb; tp.d[7] = wvlb_t; tp.K[7] = 2048;
  k_transpose8<<<dim3(40, 64, 8), dim3(32, 8), 0, stream>>>(tp);

  k_encpack<<<340, 256, 0, stream>>>(enc, etxt, eimg, elbl);

  // Q = hs @ Wq scaled by D^-0.5  (256x320 tiles, grid 256 = 1 full round)
  gemm8p<1><<<256, 512, 0, stream>>>(hsb, wq_t, qbuf, 16384, 1280, 1280,
                                     0.125f, nullptr, nullptr);
  // all 6 KV projections, one launch (prefetched 2-phase)
  kv_gemm<<<dim3(10, 5, 2), 256, 0, stream>>>(etxt, eimg, elbl,
                                              wk_t, wv_t, wkip_t, wvip_t, wklb_t, wvlb_t,
                                              ktxt, vtxt, kimg, vimg, klbl, vlbl);

  attn_kern<<<dim3(32, N_H, N_B), 256, 0, stream>>>(qbuf, ktxt, vtxt, kimg, vimg,
                                                    klbl, vlbl, attn);
  // out = attn @ Wo + bo + hs
  gemm8p<2><<<256, 512, 0, stream>>>(attn, wo_t, d_out, 16384, 1280, 1280,
                                     1.f, bo, hs);
}